// Round 4
// baseline (2523.003 us; speedup 1.0000x reference)
//
#include <hip/hip_runtime.h>

#define NROWS 1000000
#define F 128
#define HID 128
#define NC 16

typedef float f4 __attribute__((ext_vector_type(4)));

// ---------------- index pipeline ----------------

__global__ void k_firstocc(const int* __restrict__ edge, unsigned* __restrict__ focc) {
    int i = blockIdx.x * 256 + threadIdx.x;
    if (i < NROWS) {
        int s = edge[2 * i];
        atomicMin(&focc[s], (unsigned)i);
    }
}

__global__ void k_flagscan(const int* __restrict__ edge, const unsigned* __restrict__ focc,
                           unsigned* __restrict__ ranks, unsigned* __restrict__ bsums) {
    int t = threadIdx.x;
    int i = blockIdx.x * 256 + t;
    unsigned flag = 0;
    if (i < NROWS) {
        int s = edge[2 * i];
        flag = (focc[s] == (unsigned)i) ? 1u : 0u;
    }
    unsigned long long b = __ballot(flag);
    int lane = t & 63, w = t >> 6;
    unsigned pre = (unsigned)__popcll(b & ((1ull << lane) - 1ull));
    __shared__ unsigned wsum[4];
    if (lane == 0) wsum[w] = (unsigned)__popcll(b);
    __syncthreads();
    unsigned off = 0;
    for (int ww = 0; ww < w; ++ww) off += wsum[ww];
    if (i < NROWS) ranks[i] = off + pre;
    if (t == 0) bsums[blockIdx.x] = wsum[0] + wsum[1] + wsum[2] + wsum[3];
}

// single-wave exclusive scan of bsums -> boffs; also writes U (= total flags) to dU[0]
__global__ void k_scan(const unsigned* __restrict__ bsums, unsigned* __restrict__ boffs,
                       unsigned* __restrict__ dU, int nb) {
    int lane = threadIdx.x;  // 64 threads
    const int per = (nb + 63) / 64;
    int base = lane * per;
    unsigned sum = 0;
    for (int j = 0; j < per; ++j) {
        int idx = base + j;
        if (idx < nb) sum += bsums[idx];
    }
    unsigned incl = sum;
    for (int off = 1; off < 64; off <<= 1) {
        unsigned v = __shfl_up(incl, off);
        if (lane >= off) incl += v;
    }
    unsigned total = __shfl(incl, 63);
    unsigned run = incl - sum;  // exclusive prefix for this lane's chunk
    for (int j = 0; j < per; ++j) {
        int idx = base + j;
        if (idx < nb) {
            boffs[idx] = run;
            run += bsums[idx];
        }
    }
    if (lane == 0) dU[0] = total;
}

__global__ void k_mapped(const int* __restrict__ edge, const unsigned* __restrict__ focc,
                         const unsigned* __restrict__ ranks, const unsigned* __restrict__ boffs,
                         unsigned* __restrict__ mapped) {
    int i = blockIdx.x * 256 + threadIdx.x;
    if (i < NROWS) {
        int s1 = edge[2 * i];
        int s2 = edge[2 * s1];
        unsigned p = focc[s2];
        mapped[i] = ranks[p] + boffs[p >> 8];
    }
}

// zero only rows [0, U) of agg (rows >= U are never scattered to and never read)
__global__ void k_zero(float* __restrict__ agg, const unsigned* __restrict__ dU) {
    size_t total = (size_t)dU[0] * (F / 4);
    f4 z = {0.f, 0.f, 0.f, 0.f};
    f4* a4 = (f4*)agg;
    size_t stride = (size_t)gridDim.x * blockDim.x;
    for (size_t i = blockIdx.x * (size_t)blockDim.x + threadIdx.x; i < total; i += stride)
        a4[i] = z;
}

// ---------------- GEMM1 (x@W1+b1, relu) fused with atomic segment-sum scatter ----------------
// block: 256 threads; thread tile 4 rows x 4 cols; 32 rows per block-iter.
// LDS: W1 64KB + xs 16KB = 80KB -> 2 blocks/CU (8 waves/CU, 2/SIMD).
// grid = 512 = exact residency (2 blocks x 256 CU): one batch, no serialized 2nd wave.

__global__ __launch_bounds__(256, 2) void k_gemm1(const float* __restrict__ x,
                                                  const float* __restrict__ W1,
                                                  const float* __restrict__ b1,
                                                  const unsigned* __restrict__ mapped,
                                                  float* __restrict__ agg) {
    __shared__ float W1s[HID * F];  // [k][c]
    __shared__ float xs[32 * F];    // [r][k]
    int t = threadIdx.x;

    const f4* W14 = (const f4*)W1;
    f4* W1s4 = (f4*)W1s;
#pragma unroll
    for (int j = 0; j < 16; ++j) W1s4[j * 256 + t] = W14[j * 256 + t];

    int cg = t & 31, rg = t >> 5;
    int c0 = cg * 4, r0 = rg * 4;
    f4 b1v = *(const f4*)&b1[c0];
    const f4* x4 = (const f4*)x;
    f4* xs4 = (f4*)xs;

    for (int tile = blockIdx.x; tile < NROWS / 32; tile += gridDim.x) {
        int rowBase = tile * 32;
        __syncthreads();  // xs free (also covers W1 staging on first iter)
#pragma unroll
        for (int j = 0; j < 4; ++j) xs4[j * 256 + t] = x4[rowBase * 32 + j * 256 + t];
        __syncthreads();

        f4 acc[4];
#pragma unroll
        for (int rr = 0; rr < 4; ++rr) acc[rr] = b1v;

#pragma unroll 4
        for (int k0 = 0; k0 < F; k0 += 4) {
            f4 wv0 = *(const f4*)&W1s[(k0 + 0) * F + c0];
            f4 wv1 = *(const f4*)&W1s[(k0 + 1) * F + c0];
            f4 wv2 = *(const f4*)&W1s[(k0 + 2) * F + c0];
            f4 wv3 = *(const f4*)&W1s[(k0 + 3) * F + c0];
#pragma unroll
            for (int rr = 0; rr < 4; ++rr) {
                f4 xv = *(const f4*)&xs[(r0 + rr) * F + k0];
                acc[rr] += xv[0] * wv0;
                acc[rr] += xv[1] * wv1;
                acc[rr] += xv[2] * wv2;
                acc[rr] += xv[3] * wv3;
            }
        }

#pragma unroll
        for (int rr = 0; rr < 4; ++rr) {
            unsigned m = mapped[rowBase + r0 + rr];
            float* dst = &agg[(size_t)m * F + c0];
#pragma unroll
            for (int cc = 0; cc < 4; ++cc) {
                float h = acc[rr][cc];
                h = h > 0.f ? h : 0.f;
                unsafeAtomicAdd(&dst[cc], h);
            }
        }
    }
}

// ---------------- GEMM2: out = relu(agg)@W2 + b2 ----------------
// block 256 = 4 waves; each wave: 64 rows x 16 cols; thread tile 4 rows x 4 cols.
// rows >= U: agg row is identically zero -> out = b2, no agg read, no k-loop.

__global__ __launch_bounds__(256, 2) void k_gemm2(const float* __restrict__ agg,
                                                  const float* __restrict__ W2,
                                                  const float* __restrict__ b2,
                                                  const unsigned* __restrict__ dU,
                                                  float* __restrict__ out) {
    __shared__ float W2s[HID * NC];  // [k][c] 8KB
    int t = threadIdx.x;
    f4* W2s4 = (f4*)W2s;
    const f4* W24 = (const f4*)W2;
    W2s4[t] = W24[t];
    W2s4[256 + t] = W24[256 + t];
    const int U = (int)dU[0];
    __syncthreads();

    int lane = t & 63, w = t >> 6;
    int cg = lane & 3, rg = lane >> 2;
    int c0 = cg * 4;
    f4 b2v = *(const f4*)&b2[c0];
    const int ntiles = (NROWS + 255) / 256;

    for (int tile = blockIdx.x; tile < ntiles; tile += gridDim.x) {
        int rowBase = tile * 256 + w * 64 + rg * 4;

        if (rowBase >= U) {
            // pure-b2 region: agg rows are identically zero
#pragma unroll
            for (int rr = 0; rr < 4; ++rr) {
                int r = rowBase + rr;
                if (r < NROWS) *(f4*)&out[(size_t)r * NC + c0] = b2v;
            }
            continue;
        }

        f4 acc[4];
#pragma unroll
        for (int rr = 0; rr < 4; ++rr) acc[rr] = (f4){0.f, 0.f, 0.f, 0.f};

        if (rowBase + 4 <= U) {  // U <= NROWS, so also in-bounds
#pragma unroll 4
            for (int k0 = 0; k0 < HID; k0 += 4) {
                f4 wv0 = *(const f4*)&W2s[(k0 + 0) * NC + c0];
                f4 wv1 = *(const f4*)&W2s[(k0 + 1) * NC + c0];
                f4 wv2 = *(const f4*)&W2s[(k0 + 2) * NC + c0];
                f4 wv3 = *(const f4*)&W2s[(k0 + 3) * NC + c0];
#pragma unroll
                for (int rr = 0; rr < 4; ++rr) {
                    f4 av = *(const f4*)&agg[(size_t)(rowBase + rr) * HID + k0];
#pragma unroll
                    for (int kk = 0; kk < 4; ++kk) av[kk] = av[kk] > 0.f ? av[kk] : 0.f;
                    acc[rr] += av[0] * wv0;
                    acc[rr] += av[1] * wv1;
                    acc[rr] += av[2] * wv2;
                    acc[rr] += av[3] * wv3;
                }
            }
#pragma unroll
            for (int rr = 0; rr < 4; ++rr)
                *(f4*)&out[(size_t)(rowBase + rr) * NC + c0] = acc[rr] + b2v;
        } else {
            // straddles U: per-row guards
            for (int k0 = 0; k0 < HID; k0 += 4) {
                f4 wv0 = *(const f4*)&W2s[(k0 + 0) * NC + c0];
                f4 wv1 = *(const f4*)&W2s[(k0 + 1) * NC + c0];
                f4 wv2 = *(const f4*)&W2s[(k0 + 2) * NC + c0];
                f4 wv3 = *(const f4*)&W2s[(k0 + 3) * NC + c0];
                for (int rr = 0; rr < 4; ++rr) {
                    int r = rowBase + rr;
                    if (r < U) {
                        f4 av = *(const f4*)&agg[(size_t)r * HID + k0];
                        for (int kk = 0; kk < 4; ++kk) av[kk] = av[kk] > 0.f ? av[kk] : 0.f;
                        acc[rr] += av[0] * wv0;
                        acc[rr] += av[1] * wv1;
                        acc[rr] += av[2] * wv2;
                        acc[rr] += av[3] * wv3;
                    }
                }
            }
            for (int rr = 0; rr < 4; ++rr) {
                int r = rowBase + rr;
                if (r < NROWS) *(f4*)&out[(size_t)r * NC + c0] = acc[rr] + b2v;
            }
        }
    }
}

// ---------------- launch ----------------

extern "C" void kernel_launch(void* const* d_in, const int* in_sizes, int n_in,
                              void* d_out, int out_size, void* d_ws, size_t ws_size,
                              hipStream_t stream) {
    const float* x = (const float*)d_in[0];
    const int* edge = (const int*)d_in[1];
    const float* W1 = (const float*)d_in[2];
    const float* b1 = (const float*)d_in[3];
    const float* W2 = (const float*)d_in[4];
    const float* b2 = (const float*)d_in[5];
    float* out = (float*)d_out;

    char* ws = (char*)d_ws;
    float* agg = (float*)ws;                           // 512,000,000 B
    unsigned* focc = (unsigned*)(ws + 512000000);      // 4,000,000 B
    unsigned* ranks = (unsigned*)(ws + 516000000);     // 4,000,000 B
    unsigned* mapped = (unsigned*)(ws + 520000000);    // 4,000,000 B
    unsigned* bsums = (unsigned*)(ws + 524000000);     // 16,384 B
    unsigned* boffs = (unsigned*)(ws + 524016384);     // 16,384 B
    unsigned* dU = (unsigned*)(ws + 524032768);        // 4 B

    hipMemsetAsync(focc, 0xFF, (size_t)NROWS * 4, stream);

    const int nb = (NROWS + 255) / 256;  // 3907
    k_firstocc<<<nb, 256, 0, stream>>>(edge, focc);
    k_flagscan<<<nb, 256, 0, stream>>>(edge, focc, ranks, bsums);
    k_scan<<<1, 64, 0, stream>>>(bsums, boffs, dU, nb);
    k_zero<<<4096, 256, 0, stream>>>(agg, dU);
    k_mapped<<<nb, 256, 0, stream>>>(edge, focc, ranks, boffs, mapped);
    k_gemm1<<<512, 256, 0, stream>>>(x, W1, b1, mapped, agg);
    k_gemm2<<<2048, 256, 0, stream>>>(agg, W2, b2, dU, out);
}

// Round 5
// 1643.114 us; speedup vs baseline: 1.5355x; 1.5355x over previous
//
#include <hip/hip_runtime.h>

#define NROWS 1000000
#define F 128
#define HID 128
#define NC 16

typedef float f4 __attribute__((ext_vector_type(4)));
typedef float f2 __attribute__((ext_vector_type(2)));

// ---------------- index pipeline ----------------

__global__ void k_firstocc(const int* __restrict__ edge, unsigned* __restrict__ focc) {
    int i = blockIdx.x * 256 + threadIdx.x;
    if (i < NROWS) {
        int s = edge[2 * i];
        atomicMin(&focc[s], (unsigned)i);
    }
}

__global__ void k_flagscan(const int* __restrict__ edge, const unsigned* __restrict__ focc,
                           unsigned* __restrict__ ranks, unsigned* __restrict__ bsums) {
    int t = threadIdx.x;
    int i = blockIdx.x * 256 + t;
    unsigned flag = 0;
    if (i < NROWS) {
        int s = edge[2 * i];
        flag = (focc[s] == (unsigned)i) ? 1u : 0u;
    }
    unsigned long long b = __ballot(flag);
    int lane = t & 63, w = t >> 6;
    unsigned pre = (unsigned)__popcll(b & ((1ull << lane) - 1ull));
    __shared__ unsigned wsum[4];
    if (lane == 0) wsum[w] = (unsigned)__popcll(b);
    __syncthreads();
    unsigned off = 0;
    for (int ww = 0; ww < w; ++ww) off += wsum[ww];
    if (i < NROWS) ranks[i] = off + pre;
    if (t == 0) bsums[blockIdx.x] = wsum[0] + wsum[1] + wsum[2] + wsum[3];
}

// single-wave exclusive scan of bsums -> boffs; writes total to dTot[0]
__global__ void k_scan(const unsigned* __restrict__ bsums, unsigned* __restrict__ boffs,
                       unsigned* __restrict__ dTot, int nb) {
    int lane = threadIdx.x;  // 64 threads
    const int per = (nb + 63) / 64;
    int base = lane * per;
    unsigned sum = 0;
    for (int j = 0; j < per; ++j) {
        int idx = base + j;
        if (idx < nb) sum += bsums[idx];
    }
    unsigned incl = sum;
    for (int off = 1; off < 64; off <<= 1) {
        unsigned v = __shfl_up(incl, off);
        if (lane >= off) incl += v;
    }
    unsigned total = __shfl(incl, 63);
    unsigned run = incl - sum;
    for (int j = 0; j < per; ++j) {
        int idx = base + j;
        if (idx < nb) {
            boffs[idx] = run;
            run += bsums[idx];
        }
    }
    if (lane == 0) dTot[0] = total;
}

// mapped[i] = rank of seg[seg[i]]; optionally histogram into cnt
__global__ void k_mapped(const int* __restrict__ edge, const unsigned* __restrict__ focc,
                         const unsigned* __restrict__ ranks, const unsigned* __restrict__ boffs,
                         unsigned* __restrict__ mapped, unsigned* __restrict__ cnt) {
    int i = blockIdx.x * 256 + threadIdx.x;
    if (i < NROWS) {
        int s1 = edge[2 * i];
        int s2 = edge[2 * s1];
        unsigned p = focc[s2];
        unsigned m = ranks[p] + boffs[p >> 8];
        mapped[i] = m;
        if (cnt) atomicAdd(&cnt[m], 1u);
    }
}

// ---------------- CSR build: cnt -> row_ptr (+working copy wp), then perm ----------------

__global__ void k_blksum(const unsigned* __restrict__ cnt, unsigned* __restrict__ bsums2) {
    int t = threadIdx.x;
    size_t base = (size_t)blockIdx.x * 1024 + (size_t)t * 4;
    uint4 v = *(const uint4*)&cnt[base];
    unsigned s = v.x + v.y + v.z + v.w;
    for (int off = 1; off < 64; off <<= 1) s += __shfl_xor(s, off);
    __shared__ unsigned ws_[4];
    if ((t & 63) == 0) ws_[t >> 6] = s;
    __syncthreads();
    if (t == 0) bsums2[blockIdx.x] = ws_[0] + ws_[1] + ws_[2] + ws_[3];
}

__global__ void k_scanfill(const unsigned* __restrict__ cnt, const unsigned* __restrict__ boffs2,
                           unsigned* __restrict__ row_ptr, unsigned* __restrict__ wp) {
    int t = threadIdx.x;
    size_t base = (size_t)blockIdx.x * 1024 + (size_t)t * 4;
    uint4 v = *(const uint4*)&cnt[base];
    unsigned s = v.x + v.y + v.z + v.w;
    unsigned incl = s;
    int lane = t & 63;
    for (int off = 1; off < 64; off <<= 1) {
        unsigned q = __shfl_up(incl, off);
        if (lane >= off) incl += q;
    }
    __shared__ unsigned wsum[4];
    if (lane == 63) wsum[t >> 6] = incl;
    __syncthreads();
    unsigned wo = 0;
    for (int w = 0; w < (t >> 6); ++w) wo += wsum[w];
    unsigned ex = boffs2[blockIdx.x] + wo + (incl - s);
    uint4 rv;
    rv.x = ex;
    rv.y = ex + v.x;
    rv.z = rv.y + v.y;
    rv.w = rv.z + v.z;
    if (base + 3 < NROWS) {
        *(uint4*)&row_ptr[base] = rv;
        *(uint4*)&wp[base] = rv;
    } else {
        unsigned rr[4] = {rv.x, rv.y, rv.z, rv.w};
        for (int j = 0; j < 4; ++j)
            if (base + j < NROWS) { row_ptr[base + j] = rr[j]; wp[base + j] = rr[j]; }
    }
}

__global__ void k_fill(const unsigned* __restrict__ mapped, unsigned* __restrict__ wp,
                       unsigned* __restrict__ perm) {
    int i = blockIdx.x * 256 + threadIdx.x;
    if (i < NROWS) {
        unsigned m = mapped[i];
        unsigned pos = atomicAdd(&wp[m], 1u);
        perm[pos] = i;
    }
}

// ---------------- GEMM1: h = relu(x@W1 + b1), dense coalesced output ----------------

__global__ __launch_bounds__(256, 2) void k_gemm1(const float* __restrict__ x,
                                                  const float* __restrict__ W1,
                                                  const float* __restrict__ b1,
                                                  float* __restrict__ h) {
    __shared__ float W1s[HID * F];  // [k][c] 64KB
    __shared__ float xs[32 * F];    // [r][k] 16KB
    int t = threadIdx.x;

    const f4* W14 = (const f4*)W1;
    f4* W1s4 = (f4*)W1s;
#pragma unroll
    for (int j = 0; j < 16; ++j) W1s4[j * 256 + t] = W14[j * 256 + t];

    int cg = t & 31, rg = t >> 5;
    int c0 = cg * 4, r0 = rg * 4;
    f4 b1v = *(const f4*)&b1[c0];
    const f4* x4 = (const f4*)x;
    f4* xs4 = (f4*)xs;

    for (int tile = blockIdx.x; tile < NROWS / 32; tile += gridDim.x) {
        int rowBase = tile * 32;
        __syncthreads();
#pragma unroll
        for (int j = 0; j < 4; ++j) xs4[j * 256 + t] = x4[rowBase * 32 + j * 256 + t];
        __syncthreads();

        f4 acc[4];
#pragma unroll
        for (int rr = 0; rr < 4; ++rr) acc[rr] = b1v;

#pragma unroll 4
        for (int k0 = 0; k0 < F; k0 += 4) {
            f4 wv0 = *(const f4*)&W1s[(k0 + 0) * F + c0];
            f4 wv1 = *(const f4*)&W1s[(k0 + 1) * F + c0];
            f4 wv2 = *(const f4*)&W1s[(k0 + 2) * F + c0];
            f4 wv3 = *(const f4*)&W1s[(k0 + 3) * F + c0];
#pragma unroll
            for (int rr = 0; rr < 4; ++rr) {
                f4 xv = *(const f4*)&xs[(r0 + rr) * F + k0];
                acc[rr] += xv[0] * wv0;
                acc[rr] += xv[1] * wv1;
                acc[rr] += xv[2] * wv2;
                acc[rr] += xv[3] * wv3;
            }
        }

#pragma unroll
        for (int rr = 0; rr < 4; ++rr) {
            f4 hv = acc[rr];
#pragma unroll
            for (int cc = 0; cc < 4; ++cc) hv[cc] = hv[cc] > 0.f ? hv[cc] : 0.f;
            *(f4*)&h[(size_t)(rowBase + r0 + rr) * F + c0] = hv;
        }
    }
}

// ---------------- legacy fused-scatter GEMM1 (fallback when ws too small) ----------------

__global__ __launch_bounds__(256, 2) void k_gemm1_atomic(const float* __restrict__ x,
                                                         const float* __restrict__ W1,
                                                         const float* __restrict__ b1,
                                                         const unsigned* __restrict__ mapped,
                                                         float* __restrict__ agg) {
    __shared__ float W1s[HID * F];
    __shared__ float xs[32 * F];
    int t = threadIdx.x;
    const f4* W14 = (const f4*)W1;
    f4* W1s4 = (f4*)W1s;
#pragma unroll
    for (int j = 0; j < 16; ++j) W1s4[j * 256 + t] = W14[j * 256 + t];
    int cg = t & 31, rg = t >> 5;
    int c0 = cg * 4, r0 = rg * 4;
    f4 b1v = *(const f4*)&b1[c0];
    const f4* x4 = (const f4*)x;
    f4* xs4 = (f4*)xs;
    for (int tile = blockIdx.x; tile < NROWS / 32; tile += gridDim.x) {
        int rowBase = tile * 32;
        __syncthreads();
#pragma unroll
        for (int j = 0; j < 4; ++j) xs4[j * 256 + t] = x4[rowBase * 32 + j * 256 + t];
        __syncthreads();
        f4 acc[4];
#pragma unroll
        for (int rr = 0; rr < 4; ++rr) acc[rr] = b1v;
#pragma unroll 4
        for (int k0 = 0; k0 < F; k0 += 4) {
            f4 wv0 = *(const f4*)&W1s[(k0 + 0) * F + c0];
            f4 wv1 = *(const f4*)&W1s[(k0 + 1) * F + c0];
            f4 wv2 = *(const f4*)&W1s[(k0 + 2) * F + c0];
            f4 wv3 = *(const f4*)&W1s[(k0 + 3) * F + c0];
#pragma unroll
            for (int rr = 0; rr < 4; ++rr) {
                f4 xv = *(const f4*)&xs[(r0 + rr) * F + k0];
                acc[rr] += xv[0] * wv0;
                acc[rr] += xv[1] * wv1;
                acc[rr] += xv[2] * wv2;
                acc[rr] += xv[3] * wv3;
            }
        }
#pragma unroll
        for (int rr = 0; rr < 4; ++rr) {
            unsigned m = mapped[rowBase + r0 + rr];
            float* dst = &agg[(size_t)m * F + c0];
#pragma unroll
            for (int cc = 0; cc < 4; ++cc) {
                float hh = acc[rr][cc];
                hh = hh > 0.f ? hh : 0.f;
                unsafeAtomicAdd(&dst[cc], hh);
            }
        }
    }
}

__global__ void k_zero(float* __restrict__ agg, const unsigned* __restrict__ dU) {
    size_t total = (size_t)dU[0] * (F / 4);
    f4 z = {0.f, 0.f, 0.f, 0.f};
    f4* a4 = (f4*)agg;
    size_t stride = (size_t)gridDim.x * blockDim.x;
    for (size_t i = blockIdx.x * (size_t)blockDim.x + threadIdx.x; i < total; i += stride)
        a4[i] = z;
}

// ---------------- gather: agg[u] = sum of h rows in bucket u (no atomics) ----------------

__global__ __launch_bounds__(256) void k_gather(const float* __restrict__ h,
                                                const unsigned* __restrict__ row_ptr,
                                                const unsigned* __restrict__ perm,
                                                const unsigned* __restrict__ dU,
                                                float* __restrict__ agg) {
    const unsigned U = dU[0];
    unsigned wid = (blockIdx.x * 256 + threadIdx.x) >> 6;
    int lane = threadIdx.x & 63;
    unsigned nw = (gridDim.x * 256) >> 6;
    for (unsigned u = wid; u < U; u += nw) {
        unsigned s = row_ptr[u], e = row_ptr[u + 1];
        f2 acc = {0.f, 0.f};
        for (unsigned j = s; j < e; ++j) {
            unsigned i = perm[j];
            acc += *(const f2*)&h[(size_t)i * F + lane * 2];
        }
        *(f2*)&agg[(size_t)u * F + lane * 2] = acc;
    }
}

// ---------------- GEMM2: out = relu(agg)@W2 + b2, LDS-staged agg tile ----------------
// 128-row tiles; thread: 2 rows x 4 cols. agg read from HBM exactly once.
// LDS agg tile XOR-swizzled per 16B chunk: c ^ ((row>>1)&7) -> 8 bank phases, conflict-free.

__global__ __launch_bounds__(256, 2) void k_gemm2(const float* __restrict__ agg,
                                                  const float* __restrict__ W2,
                                                  const float* __restrict__ b2,
                                                  const unsigned* __restrict__ dU,
                                                  float* __restrict__ out) {
    __shared__ float W2s[HID * NC];  // 8KB [k][c]
    __shared__ float sA[128 * HID];  // 64KB, swizzled chunks
    int t = threadIdx.x;
    {
        f4* d = (f4*)W2s;
        const f4* s = (const f4*)W2;
        d[t] = s[t];
        d[256 + t] = s[256 + t];
    }
    const int U = (int)dU[0];
    int cg = t & 3, rg = t >> 2;  // 4 col-groups x 64 row-groups
    int c0 = cg * 4;
    f4 b2v = *(const f4*)&b2[c0];
    const int ntiles = (NROWS + 127) / 128;
    f4* sA4 = (f4*)sA;
    const f4* agg4 = (const f4*)agg;
    const f4 z4 = {0.f, 0.f, 0.f, 0.f};
    const int ph = rg & 7;

    for (int tile = blockIdx.x; tile < ntiles; tile += gridDim.x) {
        int rowBase = tile * 128;
        __syncthreads();
#pragma unroll
        for (int j = 0; j < 16; ++j) {
            int idx = j * 256 + t;      // f4 chunk index in 128x32 tile
            int rl = idx >> 5;          // local row
            int c = idx & 31;           // chunk within row
            int r = rowBase + rl;
            sA4[rl * 32 + (c ^ ((rl >> 1) & 7))] = (r < U) ? agg4[(size_t)r * 32 + c] : z4;
        }
        __syncthreads();

        f4 acc0 = z4, acc1 = z4;
#pragma unroll 4
        for (int k0 = 0; k0 < HID; k0 += 4) {
            f4 wv0 = *(const f4*)&W2s[(k0 + 0) * NC + c0];
            f4 wv1 = *(const f4*)&W2s[(k0 + 1) * NC + c0];
            f4 wv2 = *(const f4*)&W2s[(k0 + 2) * NC + c0];
            f4 wv3 = *(const f4*)&W2s[(k0 + 3) * NC + c0];
            f4 a0 = sA4[(rg * 2 + 0) * 32 + ((k0 >> 2) ^ ph)];
            f4 a1 = sA4[(rg * 2 + 1) * 32 + ((k0 >> 2) ^ ph)];
#pragma unroll
            for (int kk = 0; kk < 4; ++kk) {
                a0[kk] = a0[kk] > 0.f ? a0[kk] : 0.f;
                a1[kk] = a1[kk] > 0.f ? a1[kk] : 0.f;
            }
            acc0 += a0[0] * wv0 + a0[1] * wv1 + a0[2] * wv2 + a0[3] * wv3;
            acc1 += a1[0] * wv0 + a1[1] * wv1 + a1[2] * wv2 + a1[3] * wv3;
        }
        int r0w = rowBase + rg * 2;
        if (r0w < NROWS) *(f4*)&out[(size_t)r0w * NC + c0] = acc0 + b2v;
        if (r0w + 1 < NROWS) *(f4*)&out[(size_t)(r0w + 1) * NC + c0] = acc1 + b2v;
    }
}

// ---------------- launch ----------------

extern "C" void kernel_launch(void* const* d_in, const int* in_sizes, int n_in,
                              void* d_out, int out_size, void* d_ws, size_t ws_size,
                              hipStream_t stream) {
    const float* x = (const float*)d_in[0];
    const int* edge = (const int*)d_in[1];
    const float* W1 = (const float*)d_in[2];
    const float* b1 = (const float*)d_in[3];
    const float* W2 = (const float*)d_in[4];
    const float* b2 = (const float*)d_in[5];
    float* out = (float*)d_out;
    char* ws = (char*)d_ws;

    const int nb = (NROWS + 255) / 256;     // 3907
    const int nb2 = 977;                    // ceil(1000448/1024); cnt padded to 1000448

    const size_t NEED = 1052042784;

    if (ws_size >= NEED) {
        // ---- primary path: dense h + CSR gather (no fat atomics) ----
        float* h = (float*)ws;                              // 512,000,000
        float* agg = (float*)(ws + 512000000);              // 512,000,000
        unsigned* focc = (unsigned*)(ws + 1024000000);      // 4,000,000
        unsigned* ranks = (unsigned*)(ws + 1028000000);     // 4,000,000
        unsigned* mapped = (unsigned*)(ws + 1032000000);    // 4,000,000
        unsigned* cnt = (unsigned*)(ws + 1036000000);       // 4,001,792 (padded)
        unsigned* row_ptr = (unsigned*)(ws + 1040001792);   // 4,000,016 (N+1)
        unsigned* wp = (unsigned*)(ws + 1044001808);        // 4,000,000
        unsigned* perm = (unsigned*)(ws + 1048001808);      // 4,000,000
        unsigned* bsums = (unsigned*)(ws + 1052001808);     // 16,384
        unsigned* boffs = (unsigned*)(ws + 1052018192);     // 16,384
        unsigned* bsums2 = (unsigned*)(ws + 1052034576);    // 4,096
        unsigned* boffs2 = (unsigned*)(ws + 1052038672);    // 4,096
        unsigned* dU = (unsigned*)(ws + 1052042768);        // 16

        hipMemsetAsync(focc, 0xFF, (size_t)NROWS * 4, stream);
        hipMemsetAsync(cnt, 0, (size_t)1000448 * 4, stream);

        k_firstocc<<<nb, 256, 0, stream>>>(edge, focc);
        k_flagscan<<<nb, 256, 0, stream>>>(edge, focc, ranks, bsums);
        k_scan<<<1, 64, 0, stream>>>(bsums, boffs, dU, nb);
        k_mapped<<<nb, 256, 0, stream>>>(edge, focc, ranks, boffs, mapped, cnt);
        k_blksum<<<nb2, 256, 0, stream>>>(cnt, bsums2);
        k_scan<<<1, 64, 0, stream>>>(bsums2, boffs2, row_ptr + NROWS, nb2);
        k_scanfill<<<nb2, 256, 0, stream>>>(cnt, boffs2, row_ptr, wp);
        k_fill<<<nb, 256, 0, stream>>>(mapped, wp, perm);
        k_gemm1<<<512, 256, 0, stream>>>(x, W1, b1, h);
        k_gather<<<2048, 256, 0, stream>>>(h, row_ptr, perm, dU, agg);
        k_gemm2<<<2048, 256, 0, stream>>>(agg, W2, b2, dU, out);
    } else {
        // ---- fallback: previous (validated) atomic-scatter path ----
        float* agg = (float*)ws;                            // 512,000,000
        unsigned* focc = (unsigned*)(ws + 512000000);
        unsigned* ranks = (unsigned*)(ws + 516000000);
        unsigned* mapped = (unsigned*)(ws + 520000000);
        unsigned* bsums = (unsigned*)(ws + 524000000);
        unsigned* boffs = (unsigned*)(ws + 524016384);
        unsigned* dU = (unsigned*)(ws + 524032768);

        hipMemsetAsync(focc, 0xFF, (size_t)NROWS * 4, stream);
        k_firstocc<<<nb, 256, 0, stream>>>(edge, focc);
        k_flagscan<<<nb, 256, 0, stream>>>(edge, focc, ranks, bsums);
        k_scan<<<1, 64, 0, stream>>>(bsums, boffs, dU, nb);
        k_zero<<<4096, 256, 0, stream>>>(agg, dU);
        k_mapped<<<nb, 256, 0, stream>>>(edge, focc, ranks, boffs, mapped, (unsigned*)nullptr);
        k_gemm1_atomic<<<512, 256, 0, stream>>>(x, W1, b1, mapped, agg);
        k_gemm2<<<2048, 256, 0, stream>>>(agg, W2, b2, dU, out);
    }
}